// Round 1
// baseline (472.632 us; speedup 1.0000x reference)
//
#include <hip/hip_runtime.h>

#define D 360
#define NAG 64
#define NB 60
#define NPAN 6
#define COV_OFF (NAG * D)
#define INIT_OFF (COV_OFF + NAG * D * D)

__device__ __forceinline__ int gshift(int i) {
    return ((i % 60) < 58) ? (i + 2) : i;
}

// ---------------- build: S (upd agents) or final cov (others) ----------------
__global__ __launch_bounds__(384) void build_kernel(
    const float* __restrict__ P, const float* __restrict__ rs,
    const int* __restrict__ init_f, const int* __restrict__ sel_f,
    float* __restrict__ out)
{
    int i = blockIdx.x;
    int ag = blockIdx.y;
    int j = threadIdx.x;
    if (j >= D) return;
    bool ini = init_f[ag] != 0, sel = sel_f[ag] != 0;
    float c = rs[ag] + 1.0f;
    const float* Pa = P + (size_t)ag * D * D;
    float* cov = out + COV_OFF + (size_t)ag * D * D;
    float v;
    if (sel && ini) {
        // S = gather(P) + (1 + c) I   (process noise 1, obs noise c on diag)
        v = Pa[(size_t)gshift(i) * D + gshift(j)];
        if (i == j) v += 1.0f + c;
    } else if (sel && !ini) {
        v = Pa[(size_t)i * D + j] + ((i == j) ? c : 0.0f);   // cov_init = P + c I
    } else {
        v = Pa[(size_t)i * D + j];                            // passthrough
    }
    cov[(size_t)i * D + j] = v;
}

__global__ __launch_bounds__(384) void build_small_kernel(
    const float* __restrict__ mean_in, const float* __restrict__ obs,
    const int* __restrict__ init_f, const int* __restrict__ sel_f,
    float* __restrict__ out)
{
    int ag = blockIdx.x, t = threadIdx.x;
    bool ini = init_f[ag] != 0, sel = sel_f[ag] != 0;
    if (t < D) {
        float v = (sel && !ini) ? obs[ag * D + t] : mean_in[ag * D + t];
        out[ag * D + t] = v;  // upd agents overwritten by solve_mean later
    }
    if (t == 0) out[INIT_OFF + ag] = (ini || sel) ? 1.0f : 0.0f;
}

// ---------------- factor: in-place GJ on the 360x60 panel slab ----------------
template<int L> __device__ __forceinline__ float vget(const float4& v) {
    if constexpr (L == 0) return v.x;
    else if constexpr (L == 1) return v.y;
    else if constexpr (L == 2) return v.z;
    else return v.w;
}
template<int L> __device__ __forceinline__ void vset(float4& v, float s) {
    if constexpr (L == 0) v.x = s;
    else if constexpr (L == 1) v.y = s;
    else if constexpr (L == 2) v.z = s;
    else v.w = s;
}

template<int K>
__device__ __forceinline__ void gj_step(float4 (&row)[15], int r, int j0,
                                        float4* prow, float* pinv_sh)
{
    const int pr = j0 + K;
    if (r == pr) {
        float pv = 1.0f / vget<K % 4>(row[K / 4]);
        #pragma unroll
        for (int q = 0; q < 15; ++q) {
            row[q].x *= pv; row[q].y *= pv; row[q].z *= pv; row[q].w *= pv;
        }
        vset<K % 4>(row[K / 4], pv);
        *pinv_sh = pv;
        #pragma unroll
        for (int q = 0; q < 15; ++q) prow[q] = row[q];
    }
    __syncthreads();
    if (r < D && r != pr) {
        float f = vget<K % 4>(row[K / 4]);
        float pv = *pinv_sh;
        #pragma unroll
        for (int q = 0; q < 15; ++q) {
            float4 pw = prow[q];
            row[q].x = fmaf(-f, pw.x, row[q].x);
            row[q].y = fmaf(-f, pw.y, row[q].y);
            row[q].z = fmaf(-f, pw.z, row[q].z);
            row[q].w = fmaf(-f, pw.w, row[q].w);
        }
        vset<K % 4>(row[K / 4], -f * pv);
    }
    __syncthreads();
}

template<int K> struct GJSteps {
    __device__ static __forceinline__ void run(float4 (&row)[15], int r, int j0,
                                               float4* prow, float* pinv_sh) {
        gj_step<K>(row, r, j0, prow, pinv_sh);
        GJSteps<K + 1>::run(row, r, j0, prow, pinv_sh);
    }
};
template<> struct GJSteps<NB> {
    __device__ static __forceinline__ void run(float4 (&)[15], int, int, float4*, float*) {}
};

__global__ __launch_bounds__(512) void factor_kernel(
    float* __restrict__ out, const int* __restrict__ init_f,
    const int* __restrict__ sel_f, int p)
{
    int ag = blockIdx.x;
    if (!(init_f[ag] && sel_f[ag])) return;
    float* M = out + COV_OFF + (size_t)ag * D * D;
    const int j0 = p * NB;
    const int r = threadIdx.x;   // rows 0..359 active of 512
    float4 row[15];
    if (r < D) {
        const float* src = M + (size_t)r * D + j0;
        #pragma unroll
        for (int q = 0; q < 15; ++q) row[q] = *(const float4*)(src + 4 * q);
    }
    __shared__ float4 prow[15];
    __shared__ float pinv_sh;
    GJSteps<0>::run(row, r, j0, prow, &pinv_sh);
    if (r < D) {
        float* dst = M + (size_t)r * D + j0;
        #pragma unroll
        for (int q = 0; q < 15; ++q) *(float4*)(dst + 4 * q) = row[q];
    }
}

// ---------------- update: M[:,ct] = (rt==p ? 0 : M) + F * Rold ----------------
__device__ __forceinline__ void mm_row(const float4 a, const float4 b0, const float4 b1,
                                       const float4 b2, const float4 b3, float acc[4]) {
    acc[0] = fmaf(a.x, b0.x, fmaf(a.y, b1.x, fmaf(a.z, b2.x, fmaf(a.w, b3.x, acc[0]))));
    acc[1] = fmaf(a.x, b0.y, fmaf(a.y, b1.y, fmaf(a.z, b2.y, fmaf(a.w, b3.y, acc[1]))));
    acc[2] = fmaf(a.x, b0.z, fmaf(a.y, b1.z, fmaf(a.z, b2.z, fmaf(a.w, b3.z, acc[2]))));
    acc[3] = fmaf(a.x, b0.w, fmaf(a.y, b1.w, fmaf(a.z, b2.w, fmaf(a.w, b3.w, acc[3]))));
}

__global__ __launch_bounds__(256) void update_kernel(
    float* __restrict__ out, const int* __restrict__ init_f,
    const int* __restrict__ sel_f, int p)
{
    int ag = blockIdx.x;
    if (!(init_f[ag] && sel_f[ag])) return;
    int ct = blockIdx.y + (blockIdx.y >= p ? 1 : 0);   // col-tile, skipping the panel
    float* M = out + COV_OFF + (size_t)ag * D * D;
    const int j0 = p * NB, c0 = ct * NB;
    __shared__ float R[NB][NB + 8];   // pre-factor pivot rows   [k][j]
    __shared__ float F[NB][NB + 8];   // factored panel columns  [r][k]
    const int t = threadIdx.x;
    for (int idx = t; idx < NB * 15; idx += 256) {
        int k = idx / 15, q = idx % 15;
        float4 v = *(const float4*)(M + (size_t)(j0 + k) * D + c0 + 4 * q);
        *(float4*)&R[k][4 * q] = v;
    }
    const int tx = t % 16, ty = t / 16;
    for (int rt = 0; rt < NPAN; ++rt) {
        const int r0 = rt * NB;
        __syncthreads();
        for (int idx = t; idx < NB * 15; idx += 256) {
            int rr = idx / 15, q = idx % 15;
            float4 v = *(const float4*)(M + (size_t)(r0 + rr) * D + j0 + 4 * q);
            *(float4*)&F[rr][4 * q] = v;
        }
        __syncthreads();
        if (tx < 15 && ty < 15) {
            float acc[4][4];
            #pragma unroll
            for (int i = 0; i < 4; ++i)
                #pragma unroll
                for (int j = 0; j < 4; ++j) acc[i][j] = 0.0f;
            for (int kq = 0; kq < 15; ++kq) {
                float4 a0 = *(const float4*)&F[4 * ty + 0][4 * kq];
                float4 a1 = *(const float4*)&F[4 * ty + 1][4 * kq];
                float4 a2 = *(const float4*)&F[4 * ty + 2][4 * kq];
                float4 a3 = *(const float4*)&F[4 * ty + 3][4 * kq];
                float4 b0 = *(const float4*)&R[4 * kq + 0][4 * tx];
                float4 b1 = *(const float4*)&R[4 * kq + 1][4 * tx];
                float4 b2 = *(const float4*)&R[4 * kq + 2][4 * tx];
                float4 b3 = *(const float4*)&R[4 * kq + 3][4 * tx];
                mm_row(a0, b0, b1, b2, b3, acc[0]);
                mm_row(a1, b0, b1, b2, b3, acc[1]);
                mm_row(a2, b0, b1, b2, b3, acc[2]);
                mm_row(a3, b0, b1, b2, b3, acc[3]);
            }
            #pragma unroll
            for (int i = 0; i < 4; ++i) {
                float* dst = M + (size_t)(r0 + 4 * ty + i) * D + c0 + 4 * tx;
                float4 base;
                if (rt == p) { base = make_float4(0.f, 0.f, 0.f, 0.f); }
                else         { base = *(const float4*)dst; }
                float4 o;
                o.x = base.x + acc[i][0];
                o.y = base.y + acc[i][1];
                o.z = base.z + acc[i][2];
                o.w = base.w + acc[i][3];
                *(float4*)dst = o;
            }
        }
    }
}

// ---------------- mean: m_upd = obs - c * Sinv * (obs - m_pred) ----------------
__global__ __launch_bounds__(384) void solve_mean_kernel(
    float* __restrict__ out, const float* __restrict__ mean_in,
    const float* __restrict__ obs, const float* __restrict__ rs,
    const int* __restrict__ init_f, const int* __restrict__ sel_f)
{
    int ag = blockIdx.x;
    if (!(init_f[ag] && sel_f[ag])) return;
    const float* Minv = out + COV_OFF + (size_t)ag * D * D;
    __shared__ float dsh[D];
    int t = threadIdx.x;
    if (t < D) dsh[t] = obs[ag * D + t] - mean_in[ag * D + gshift(t)];
    __syncthreads();
    if (t < D) {
        float acc = 0.0f;
        #pragma unroll 8
        for (int j = 0; j < D; ++j)
            acc = fmaf(Minv[(size_t)j * D + t], dsh[j], acc);  // Sinv symmetric -> coalesced
        float c = rs[ag] + 1.0f;
        out[ag * D + t] = obs[ag * D + t] - c * acc;
    }
}

// ---------------- finalize: cov = c*I - c^2 * Sinv (upd agents) ----------------
__global__ __launch_bounds__(384) void finalize_kernel(
    float* __restrict__ out, const float* __restrict__ rs,
    const int* __restrict__ init_f, const int* __restrict__ sel_f)
{
    int i = blockIdx.x, ag = blockIdx.y, j = threadIdx.x;
    if (j >= D) return;
    if (!(init_f[ag] && sel_f[ag])) return;
    float c = rs[ag] + 1.0f;
    float* cov = out + COV_OFF + (size_t)ag * D * D;
    float v = cov[(size_t)i * D + j];
    cov[(size_t)i * D + j] = ((i == j) ? c : 0.0f) - c * c * v;
}

extern "C" void kernel_launch(void* const* d_in, const int* in_sizes, int n_in,
                              void* d_out, int out_size, void* d_ws, size_t ws_size,
                              hipStream_t stream) {
    const float* mean_in    = (const float*)d_in[0];
    const float* P          = (const float*)d_in[1];
    const float* obs        = (const float*)d_in[2];
    const float* rs         = (const float*)d_in[3];
    const int*   initialized = (const int*)d_in[4];
    const int*   selected    = (const int*)d_in[5];
    float* out = (float*)d_out;

    build_kernel<<<dim3(D, NAG), 384, 0, stream>>>(P, rs, initialized, selected, out);
    build_small_kernel<<<NAG, 384, 0, stream>>>(mean_in, obs, initialized, selected, out);
    for (int p = 0; p < NPAN; ++p) {
        factor_kernel<<<NAG, 512, 0, stream>>>(out, initialized, selected, p);
        update_kernel<<<dim3(NAG, NPAN - 1), 256, 0, stream>>>(out, initialized, selected, p);
    }
    solve_mean_kernel<<<NAG, 384, 0, stream>>>(out, mean_in, obs, rs, initialized, selected);
    finalize_kernel<<<dim3(D, NAG), 384, 0, stream>>>(out, rs, initialized, selected);
}

// Round 2
// 320.382 us; speedup vs baseline: 1.4752x; 1.4752x over previous
//
#include <hip/hip_runtime.h>

#define D 360
#define NAG 64
#define NB 60
#define NPAN 6
#define COV_OFF (NAG * D)
#define INIT_OFF (COV_OFF + NAG * D * D)

__device__ __forceinline__ int gshift(int i) {
    return ((i % 60) < 58) ? (i + 2) : i;
}

// ---------------- build: S (upd agents) or final cov (others) ----------------
__global__ __launch_bounds__(384) void build_kernel(
    const float* __restrict__ P, const float* __restrict__ rs,
    const int* __restrict__ init_f, const int* __restrict__ sel_f,
    float* __restrict__ out)
{
    int i = blockIdx.x;
    int ag = blockIdx.y;
    int j = threadIdx.x;
    if (j >= D) return;
    bool ini = init_f[ag] != 0, sel = sel_f[ag] != 0;
    float c = rs[ag] + 1.0f;
    const float* Pa = P + (size_t)ag * D * D;
    float* cov = out + COV_OFF + (size_t)ag * D * D;
    float v;
    if (sel && ini) {
        // S = gather(P) + (1 + c) I   (process noise 1, obs noise c on diag)
        v = Pa[(size_t)gshift(i) * D + gshift(j)];
        if (i == j) v += 1.0f + c;
    } else if (sel && !ini) {
        v = Pa[(size_t)i * D + j] + ((i == j) ? c : 0.0f);   // cov_init = P + c I
    } else {
        v = Pa[(size_t)i * D + j];                            // passthrough
    }
    cov[(size_t)i * D + j] = v;
}

__global__ __launch_bounds__(384) void build_small_kernel(
    const float* __restrict__ mean_in, const float* __restrict__ obs,
    const int* __restrict__ init_f, const int* __restrict__ sel_f,
    float* __restrict__ out)
{
    int ag = blockIdx.x, t = threadIdx.x;
    bool ini = init_f[ag] != 0, sel = sel_f[ag] != 0;
    if (t < D) {
        float v = (sel && !ini) ? obs[ag * D + t] : mean_in[ag * D + t];
        out[ag * D + t] = v;  // upd agents overwritten by solve_mean later
    }
    if (t == 0) out[INIT_OFF + ag] = (ini || sel) ? 1.0f : 0.0f;
}

// ---------------- 4x4 in-place GJ inverse (no pivoting; SPD blocks) ----------
__device__ __forceinline__ void inv4(float4& m0, float4& m1, float4& m2, float4& m3)
{
    float pv, f;
    // step 0: pivot m0.x
    pv = 1.0f / m0.x;
    m0.y *= pv; m0.z *= pv; m0.w *= pv; m0.x = pv;
    f = m1.x; m1.y = fmaf(-f, m0.y, m1.y); m1.z = fmaf(-f, m0.z, m1.z); m1.w = fmaf(-f, m0.w, m1.w); m1.x = -f * pv;
    f = m2.x; m2.y = fmaf(-f, m0.y, m2.y); m2.z = fmaf(-f, m0.z, m2.z); m2.w = fmaf(-f, m0.w, m2.w); m2.x = -f * pv;
    f = m3.x; m3.y = fmaf(-f, m0.y, m3.y); m3.z = fmaf(-f, m0.z, m3.z); m3.w = fmaf(-f, m0.w, m3.w); m3.x = -f * pv;
    // step 1: pivot m1.y
    pv = 1.0f / m1.y;
    m1.x *= pv; m1.z *= pv; m1.w *= pv; m1.y = pv;
    f = m0.y; m0.x = fmaf(-f, m1.x, m0.x); m0.z = fmaf(-f, m1.z, m0.z); m0.w = fmaf(-f, m1.w, m0.w); m0.y = -f * pv;
    f = m2.y; m2.x = fmaf(-f, m1.x, m2.x); m2.z = fmaf(-f, m1.z, m2.z); m2.w = fmaf(-f, m1.w, m2.w); m2.y = -f * pv;
    f = m3.y; m3.x = fmaf(-f, m1.x, m3.x); m3.z = fmaf(-f, m1.z, m3.z); m3.w = fmaf(-f, m1.w, m3.w); m3.y = -f * pv;
    // step 2: pivot m2.z
    pv = 1.0f / m2.z;
    m2.x *= pv; m2.y *= pv; m2.w *= pv; m2.z = pv;
    f = m0.z; m0.x = fmaf(-f, m2.x, m0.x); m0.y = fmaf(-f, m2.y, m0.y); m0.w = fmaf(-f, m2.w, m0.w); m0.z = -f * pv;
    f = m1.z; m1.x = fmaf(-f, m2.x, m1.x); m1.y = fmaf(-f, m2.y, m1.y); m1.w = fmaf(-f, m2.w, m1.w); m1.z = -f * pv;
    f = m3.z; m3.x = fmaf(-f, m2.x, m3.x); m3.y = fmaf(-f, m2.y, m3.y); m3.w = fmaf(-f, m2.w, m3.w); m3.z = -f * pv;
    // step 3: pivot m3.w
    pv = 1.0f / m3.w;
    m3.x *= pv; m3.y *= pv; m3.z *= pv; m3.w = pv;
    f = m0.w; m0.x = fmaf(-f, m3.x, m0.x); m0.y = fmaf(-f, m3.y, m0.y); m0.z = fmaf(-f, m3.z, m0.z); m0.w = -f * pv;
    f = m1.w; m1.x = fmaf(-f, m3.x, m1.x); m1.y = fmaf(-f, m3.y, m1.y); m1.z = fmaf(-f, m3.z, m1.z); m1.w = -f * pv;
    f = m2.w; m2.x = fmaf(-f, m3.x, m2.x); m2.y = fmaf(-f, m3.y, m2.y); m2.z = fmaf(-f, m3.z, m2.z); m2.w = -f * pv;
}

// ---------------- factor: block-pivot (mb=4) GJ on the 360x60 panel slab -----
// One barrier per block step via double-buffered raw pivot-row slab in LDS.
__global__ __launch_bounds__(384) void factor_kernel(
    float* __restrict__ out, const int* __restrict__ init_f,
    const int* __restrict__ sel_f, int p)
{
    int ag = blockIdx.x;
    if (!(init_f[ag] && sel_f[ag])) return;
    float* M = out + COV_OFF + (size_t)ag * D * D;
    const int j0 = p * NB;
    const int r = threadIdx.x;       // one row per thread, rows 0..359 of 384
    const int rel = r - j0;          // panel-relative row index
    float4 row[15];
    if (r < D) {
        const float* src = M + (size_t)r * D + j0;
        #pragma unroll
        for (int q = 0; q < 15; ++q) row[q] = *(const float4*)(src + 4 * q);
    }
    __shared__ float4 praw[2][4][15];    // double-buffered raw pivot rows
    if (rel >= 0 && rel < 4) {
        #pragma unroll
        for (int q = 0; q < 15; ++q) praw[0][rel][q] = row[q];
    }
    __syncthreads();
    #pragma unroll
    for (int kb = 0; kb < 15; ++kb) {
        const int buf = kb & 1;
        // 4x4 pivot block (rows of praw at float4 column kb), inverted redundantly
        float4 m0 = praw[buf][0][kb];
        float4 m1 = praw[buf][1][kb];
        float4 m2 = praw[buf][2][kb];
        float4 m3 = praw[buf][3][kb];
        inv4(m0, m1, m2, m3);
        if (r < D) {
            const bool is_piv = (rel >= 4 * kb) && (rel < 4 * kb + 4);
            float4 sc;
            if (is_piv) {
                const int i = rel - 4 * kb;
                sc = (i == 0) ? m0 : (i == 1) ? m1 : (i == 2) ? m2 : m3;  // Binv row
                #pragma unroll
                for (int q = 0; q < 15; ++q)
                    if (q != kb) row[q] = make_float4(0.f, 0.f, 0.f, 0.f);
            } else {
                float4 fr = row[kb];            // pivot-col coefficients
                sc.x = -(fr.x * m0.x + fr.y * m1.x + fr.z * m2.x + fr.w * m3.x);
                sc.y = -(fr.x * m0.y + fr.y * m1.y + fr.z * m2.y + fr.w * m3.y);
                sc.z = -(fr.x * m0.z + fr.y * m1.z + fr.z * m2.z + fr.w * m3.z);
                sc.w = -(fr.x * m0.w + fr.y * m1.w + fr.z * m2.w + fr.w * m3.w);
            }
            // uniform rank-4 update: row += sc * raw_pivot_rows   (pivot rows: 0 + Binv*raw)
            #pragma unroll
            for (int q = 0; q < 15; ++q) {
                if (q == kb) continue;
                float4 p0 = praw[buf][0][q];
                float4 p1 = praw[buf][1][q];
                float4 p2 = praw[buf][2][q];
                float4 p3 = praw[buf][3][q];
                row[q].x = fmaf(sc.x, p0.x, fmaf(sc.y, p1.x, fmaf(sc.z, p2.x, fmaf(sc.w, p3.x, row[q].x))));
                row[q].y = fmaf(sc.x, p0.y, fmaf(sc.y, p1.y, fmaf(sc.z, p2.y, fmaf(sc.w, p3.y, row[q].y))));
                row[q].z = fmaf(sc.x, p0.z, fmaf(sc.y, p1.z, fmaf(sc.z, p2.z, fmaf(sc.w, p3.z, row[q].z))));
                row[q].w = fmaf(sc.x, p0.w, fmaf(sc.y, p1.w, fmaf(sc.z, p2.w, fmaf(sc.w, p3.w, row[q].w))));
            }
            row[kb] = sc;   // pivot rows: Binv row; others: -f*Binv
            // stage NEXT block step's raw pivot rows into the other buffer
            if (kb < 14 && rel >= 4 * (kb + 1) && rel < 4 * (kb + 1) + 4) {
                const int i = rel - 4 * (kb + 1);
                #pragma unroll
                for (int q = 0; q < 15; ++q) praw[buf ^ 1][i][q] = row[q];
            }
        }
        __syncthreads();
    }
    if (r < D) {
        float* dst = M + (size_t)r * D + j0;
        #pragma unroll
        for (int q = 0; q < 15; ++q) *(float4*)(dst + 4 * q) = row[q];
    }
}

// ---------------- update: M[:,ct] = (rt==p ? 0 : M) + F * Rold ----------------
__device__ __forceinline__ void mm_row(const float4 a, const float4 b0, const float4 b1,
                                       const float4 b2, const float4 b3, float acc[4]) {
    acc[0] = fmaf(a.x, b0.x, fmaf(a.y, b1.x, fmaf(a.z, b2.x, fmaf(a.w, b3.x, acc[0]))));
    acc[1] = fmaf(a.x, b0.y, fmaf(a.y, b1.y, fmaf(a.z, b2.y, fmaf(a.w, b3.y, acc[1]))));
    acc[2] = fmaf(a.x, b0.z, fmaf(a.y, b1.z, fmaf(a.z, b2.z, fmaf(a.w, b3.z, acc[2]))));
    acc[3] = fmaf(a.x, b0.w, fmaf(a.y, b1.w, fmaf(a.z, b2.w, fmaf(a.w, b3.w, acc[3]))));
}

__global__ __launch_bounds__(256) void update_kernel(
    float* __restrict__ out, const int* __restrict__ init_f,
    const int* __restrict__ sel_f, int p)
{
    int ag = blockIdx.x;
    if (!(init_f[ag] && sel_f[ag])) return;
    int ct = blockIdx.y + (blockIdx.y >= p ? 1 : 0);   // col-tile, skipping the panel
    float* M = out + COV_OFF + (size_t)ag * D * D;
    const int j0 = p * NB, c0 = ct * NB;
    __shared__ float R[NB][NB + 8];   // pre-factor pivot rows   [k][j]
    __shared__ float F[NB][NB + 8];   // factored panel columns  [r][k]
    const int t = threadIdx.x;
    for (int idx = t; idx < NB * 15; idx += 256) {
        int k = idx / 15, q = idx % 15;
        float4 v = *(const float4*)(M + (size_t)(j0 + k) * D + c0 + 4 * q);
        *(float4*)&R[k][4 * q] = v;
    }
    const int tx = t % 16, ty = t / 16;
    for (int rr = 0; rr < 2; ++rr) {
        const int rt = (int)blockIdx.z * 2 + rr;       // 2 row-tiles per WG
        const int r0 = rt * NB;
        __syncthreads();
        for (int idx = t; idx < NB * 15; idx += 256) {
            int rrw = idx / 15, q = idx % 15;
            float4 v = *(const float4*)(M + (size_t)(r0 + rrw) * D + j0 + 4 * q);
            *(float4*)&F[rrw][4 * q] = v;
        }
        __syncthreads();
        if (tx < 15 && ty < 15) {
            float acc[4][4];
            #pragma unroll
            for (int i = 0; i < 4; ++i)
                #pragma unroll
                for (int j = 0; j < 4; ++j) acc[i][j] = 0.0f;
            for (int kq = 0; kq < 15; ++kq) {
                float4 a0 = *(const float4*)&F[4 * ty + 0][4 * kq];
                float4 a1 = *(const float4*)&F[4 * ty + 1][4 * kq];
                float4 a2 = *(const float4*)&F[4 * ty + 2][4 * kq];
                float4 a3 = *(const float4*)&F[4 * ty + 3][4 * kq];
                float4 b0 = *(const float4*)&R[4 * kq + 0][4 * tx];
                float4 b1 = *(const float4*)&R[4 * kq + 1][4 * tx];
                float4 b2 = *(const float4*)&R[4 * kq + 2][4 * tx];
                float4 b3 = *(const float4*)&R[4 * kq + 3][4 * tx];
                mm_row(a0, b0, b1, b2, b3, acc[0]);
                mm_row(a1, b0, b1, b2, b3, acc[1]);
                mm_row(a2, b0, b1, b2, b3, acc[2]);
                mm_row(a3, b0, b1, b2, b3, acc[3]);
            }
            #pragma unroll
            for (int i = 0; i < 4; ++i) {
                float* dst = M + (size_t)(r0 + 4 * ty + i) * D + c0 + 4 * tx;
                float4 base;
                if (rt == p) { base = make_float4(0.f, 0.f, 0.f, 0.f); }
                else         { base = *(const float4*)dst; }
                float4 o;
                o.x = base.x + acc[i][0];
                o.y = base.y + acc[i][1];
                o.z = base.z + acc[i][2];
                o.w = base.w + acc[i][3];
                *(float4*)dst = o;
            }
        }
    }
}

// ---------------- mean: m_upd = obs - c * Sinv * (obs - m_pred) ----------------
__global__ __launch_bounds__(384) void solve_mean_kernel(
    float* __restrict__ out, const float* __restrict__ mean_in,
    const float* __restrict__ obs, const float* __restrict__ rs,
    const int* __restrict__ init_f, const int* __restrict__ sel_f)
{
    int ag = blockIdx.x;
    if (!(init_f[ag] && sel_f[ag])) return;
    const float* Minv = out + COV_OFF + (size_t)ag * D * D;
    __shared__ float dsh[D];
    int t = threadIdx.x;
    if (t < D) dsh[t] = obs[ag * D + t] - mean_in[ag * D + gshift(t)];
    __syncthreads();
    if (t < D) {
        float acc = 0.0f;
        #pragma unroll 8
        for (int j = 0; j < D; ++j)
            acc = fmaf(Minv[(size_t)j * D + t], dsh[j], acc);  // Sinv symmetric -> coalesced
        float c = rs[ag] + 1.0f;
        out[ag * D + t] = obs[ag * D + t] - c * acc;
    }
}

// ---------------- finalize: cov = c*I - c^2 * Sinv (upd agents) ----------------
__global__ __launch_bounds__(384) void finalize_kernel(
    float* __restrict__ out, const float* __restrict__ rs,
    const int* __restrict__ init_f, const int* __restrict__ sel_f)
{
    int i = blockIdx.x, ag = blockIdx.y, j = threadIdx.x;
    if (j >= D) return;
    if (!(init_f[ag] && sel_f[ag])) return;
    float c = rs[ag] + 1.0f;
    float* cov = out + COV_OFF + (size_t)ag * D * D;
    float v = cov[(size_t)i * D + j];
    cov[(size_t)i * D + j] = ((i == j) ? c : 0.0f) - c * c * v;
}

extern "C" void kernel_launch(void* const* d_in, const int* in_sizes, int n_in,
                              void* d_out, int out_size, void* d_ws, size_t ws_size,
                              hipStream_t stream) {
    const float* mean_in    = (const float*)d_in[0];
    const float* P          = (const float*)d_in[1];
    const float* obs        = (const float*)d_in[2];
    const float* rs         = (const float*)d_in[3];
    const int*   initialized = (const int*)d_in[4];
    const int*   selected    = (const int*)d_in[5];
    float* out = (float*)d_out;

    build_kernel<<<dim3(D, NAG), 384, 0, stream>>>(P, rs, initialized, selected, out);
    build_small_kernel<<<NAG, 384, 0, stream>>>(mean_in, obs, initialized, selected, out);
    for (int p = 0; p < NPAN; ++p) {
        factor_kernel<<<NAG, 384, 0, stream>>>(out, initialized, selected, p);
        update_kernel<<<dim3(NAG, NPAN - 1, 3), 256, 0, stream>>>(out, initialized, selected, p);
    }
    solve_mean_kernel<<<NAG, 384, 0, stream>>>(out, mean_in, obs, rs, initialized, selected);
    finalize_kernel<<<dim3(D, NAG), 384, 0, stream>>>(out, rs, initialized, selected);
}

// Round 3
// 312.853 us; speedup vs baseline: 1.5107x; 1.0241x over previous
//
#include <hip/hip_runtime.h>

#define D 360
#define NAG 64
#define NB 60
#define NPAN 6
#define COV_OFF (NAG * D)
#define INIT_OFF (COV_OFF + NAG * D * D)
// ping-pong R stash in d_ws: [parity][agent][ct][60][60]
#define RBOFF(par, ag, ct) ((((par) * NAG + (ag)) * 6 + (ct)) * 3600)

__device__ __forceinline__ int gshift(int i) {
    return ((i % 60) < 58) ? (i + 2) : i;
}

// ------- build: S (upd) / final cov (others) + mean/flag + R0 stash ---------
__global__ __launch_bounds__(384) void build_kernel(
    const float* __restrict__ P, const float* __restrict__ mean_in,
    const float* __restrict__ obs, const float* __restrict__ rs,
    const int* __restrict__ init_f, const int* __restrict__ sel_f,
    float* __restrict__ out, float* __restrict__ rb)
{
    const int by = blockIdx.x, ag = blockIdx.y, t = threadIdx.x;
    const bool ini = init_f[ag] != 0, sel = sel_f[ag] != 0;
    const float c = rs[ag] + 1.0f;
    if (by == 45) {   // fused "small" block: mean passthrough/init + flag
        if (t < D) {
            float v = (sel && !ini) ? obs[ag * D + t] : mean_in[ag * D + t];
            out[ag * D + t] = v;     // upd agents overwritten by solve_mean
        }
        if (t == 0) out[INIT_OFF + ag] = (ini || sel) ? 1.0f : 0.0f;
        return;
    }
    if (t >= D) return;
    const float* Pa = P + (size_t)ag * D * D;
    float* cov = out + COV_OFF + (size_t)ag * D * D;
    const int j = t;
    if (sel && ini) {
        const int gj = gshift(j);
        #pragma unroll
        for (int s = 0; s < 8; ++s) {
            const int i = by * 8 + s;
            float v = Pa[(size_t)gshift(i) * D + gj];
            if (i == j) v += 1.0f + c;           // + process(1) + obs(c)
            cov[(size_t)i * D + j] = v;
            if (i < NB && j >= NB)               // stash R slices for pass 0
                rb[RBOFF(0, ag, j / NB) + i * NB + (j % NB)] = v;
        }
    } else if (sel) {
        #pragma unroll
        for (int s = 0; s < 8; ++s) {
            const int i = by * 8 + s;
            cov[(size_t)i * D + j] = Pa[(size_t)i * D + j] + ((i == j) ? c : 0.0f);
        }
    } else {
        #pragma unroll
        for (int s = 0; s < 8; ++s) {
            const int i = by * 8 + s;
            cov[(size_t)i * D + j] = Pa[(size_t)i * D + j];
        }
    }
}

// ---------------- 4x4 in-place GJ inverse (no pivoting; SPD blocks) ----------
__device__ __forceinline__ void inv4(float4& m0, float4& m1, float4& m2, float4& m3)
{
    float pv, f;
    pv = 1.0f / m0.x;
    m0.y *= pv; m0.z *= pv; m0.w *= pv; m0.x = pv;
    f = m1.x; m1.y = fmaf(-f, m0.y, m1.y); m1.z = fmaf(-f, m0.z, m1.z); m1.w = fmaf(-f, m0.w, m1.w); m1.x = -f * pv;
    f = m2.x; m2.y = fmaf(-f, m0.y, m2.y); m2.z = fmaf(-f, m0.z, m2.z); m2.w = fmaf(-f, m0.w, m2.w); m2.x = -f * pv;
    f = m3.x; m3.y = fmaf(-f, m0.y, m3.y); m3.z = fmaf(-f, m0.z, m3.z); m3.w = fmaf(-f, m0.w, m3.w); m3.x = -f * pv;
    pv = 1.0f / m1.y;
    m1.x *= pv; m1.z *= pv; m1.w *= pv; m1.y = pv;
    f = m0.y; m0.x = fmaf(-f, m1.x, m0.x); m0.z = fmaf(-f, m1.z, m0.z); m0.w = fmaf(-f, m1.w, m0.w); m0.y = -f * pv;
    f = m2.y; m2.x = fmaf(-f, m1.x, m2.x); m2.z = fmaf(-f, m1.z, m2.z); m2.w = fmaf(-f, m1.w, m2.w); m2.y = -f * pv;
    f = m3.y; m3.x = fmaf(-f, m1.x, m3.x); m3.z = fmaf(-f, m1.z, m3.z); m3.w = fmaf(-f, m1.w, m3.w); m3.y = -f * pv;
    pv = 1.0f / m2.z;
    m2.x *= pv; m2.y *= pv; m2.w *= pv; m2.z = pv;
    f = m0.z; m0.x = fmaf(-f, m2.x, m0.x); m0.y = fmaf(-f, m2.y, m0.y); m0.w = fmaf(-f, m2.w, m0.w); m0.z = -f * pv;
    f = m1.z; m1.x = fmaf(-f, m2.x, m1.x); m1.y = fmaf(-f, m2.y, m1.y); m1.w = fmaf(-f, m2.w, m1.w); m1.z = -f * pv;
    f = m3.z; m3.x = fmaf(-f, m2.x, m3.x); m3.y = fmaf(-f, m2.y, m3.y); m3.w = fmaf(-f, m2.w, m3.w); m3.z = -f * pv;
    pv = 1.0f / m3.w;
    m3.x *= pv; m3.y *= pv; m3.z *= pv; m3.w = pv;
    f = m0.w; m0.x = fmaf(-f, m3.x, m0.x); m0.y = fmaf(-f, m3.y, m0.y); m0.z = fmaf(-f, m3.z, m0.z); m0.w = -f * pv;
    f = m1.w; m1.x = fmaf(-f, m3.x, m1.x); m1.y = fmaf(-f, m3.y, m1.y); m1.z = fmaf(-f, m3.z, m1.z); m1.w = -f * pv;
    f = m2.w; m2.x = fmaf(-f, m3.x, m2.x); m2.y = fmaf(-f, m3.y, m2.y); m2.z = fmaf(-f, m3.z, m2.z); m2.w = -f * pv;
}

// ---------------- factor: block-pivot (mb=4) GJ on the 360x60 panel slab -----
__global__ __launch_bounds__(384) void factor_kernel(
    float* __restrict__ out, const int* __restrict__ init_f,
    const int* __restrict__ sel_f, float* __restrict__ rb, int p)
{
    const int ag = blockIdx.x;
    if (!(init_f[ag] && sel_f[ag])) return;
    float* M = out + COV_OFF + (size_t)ag * D * D;
    const int j0 = p * NB;
    const int r = threadIdx.x;
    const int rel = r - j0;
    float4 row[15];
    if (r < D) {
        const float* src = M + (size_t)r * D + j0;
        #pragma unroll
        for (int q = 0; q < 15; ++q) row[q] = *(const float4*)(src + 4 * q);
    }
    __shared__ float4 praw[2][4][15];
    if (rel >= 0 && rel < 4) {
        #pragma unroll
        for (int q = 0; q < 15; ++q) praw[0][rel][q] = row[q];
    }
    __syncthreads();
    #pragma unroll
    for (int kb = 0; kb < 15; ++kb) {
        const int buf = kb & 1;
        float4 m0 = praw[buf][0][kb];
        float4 m1 = praw[buf][1][kb];
        float4 m2 = praw[buf][2][kb];
        float4 m3 = praw[buf][3][kb];
        inv4(m0, m1, m2, m3);
        if (r < D) {
            const bool is_piv = (rel >= 4 * kb) && (rel < 4 * kb + 4);
            float4 sc;
            if (is_piv) {
                const int i = rel - 4 * kb;
                sc = (i == 0) ? m0 : (i == 1) ? m1 : (i == 2) ? m2 : m3;
                #pragma unroll
                for (int q = 0; q < 15; ++q)
                    if (q != kb) row[q] = make_float4(0.f, 0.f, 0.f, 0.f);
            } else {
                float4 fr = row[kb];
                sc.x = -(fr.x * m0.x + fr.y * m1.x + fr.z * m2.x + fr.w * m3.x);
                sc.y = -(fr.x * m0.y + fr.y * m1.y + fr.z * m2.y + fr.w * m3.y);
                sc.z = -(fr.x * m0.z + fr.y * m1.z + fr.z * m2.z + fr.w * m3.z);
                sc.w = -(fr.x * m0.w + fr.y * m1.w + fr.z * m2.w + fr.w * m3.w);
            }
            #pragma unroll
            for (int q = 0; q < 15; ++q) {
                if (q == kb) continue;
                float4 p0 = praw[buf][0][q];
                float4 p1 = praw[buf][1][q];
                float4 p2 = praw[buf][2][q];
                float4 p3 = praw[buf][3][q];
                row[q].x = fmaf(sc.x, p0.x, fmaf(sc.y, p1.x, fmaf(sc.z, p2.x, fmaf(sc.w, p3.x, row[q].x))));
                row[q].y = fmaf(sc.x, p0.y, fmaf(sc.y, p1.y, fmaf(sc.z, p2.y, fmaf(sc.w, p3.y, row[q].y))));
                row[q].z = fmaf(sc.x, p0.z, fmaf(sc.y, p1.z, fmaf(sc.z, p2.z, fmaf(sc.w, p3.z, row[q].z))));
                row[q].w = fmaf(sc.x, p0.w, fmaf(sc.y, p1.w, fmaf(sc.z, p2.w, fmaf(sc.w, p3.w, row[q].w))));
            }
            row[kb] = sc;
            if (kb < 14 && rel >= 4 * (kb + 1) && rel < 4 * (kb + 1) + 4) {
                const int i = rel - 4 * (kb + 1);
                #pragma unroll
                for (int q = 0; q < 15; ++q) praw[buf ^ 1][i][q] = row[q];
            }
        }
        __syncthreads();
    }
    if (r < D) {
        float* dst = M + (size_t)r * D + j0;
        #pragma unroll
        for (int q = 0; q < 15; ++q) *(float4*)(dst + 4 * q) = row[q];
        // stash next pass's R slice for col-tile ct==p (rows of next panel)
        if (p < NPAN - 1) {
            const int nrel = r - NB * (p + 1);
            if (nrel >= 0 && nrel < NB) {
                float* rdst = rb + RBOFF((p + 1) & 1, ag, p) + nrel * NB;
                #pragma unroll
                for (int q = 0; q < 15; ++q) *(float4*)(rdst + 4 * q) = row[q];
            }
        }
    }
}

// -------- update: M[:,ct] = (rt==p?0:M) + F*R ; R from stash; stash next R ---
__device__ __forceinline__ void mm_row(const float4 a, const float4 b0, const float4 b1,
                                       const float4 b2, const float4 b3, float acc[4]) {
    acc[0] = fmaf(a.x, b0.x, fmaf(a.y, b1.x, fmaf(a.z, b2.x, fmaf(a.w, b3.x, acc[0]))));
    acc[1] = fmaf(a.x, b0.y, fmaf(a.y, b1.y, fmaf(a.z, b2.y, fmaf(a.w, b3.y, acc[1]))));
    acc[2] = fmaf(a.x, b0.z, fmaf(a.y, b1.z, fmaf(a.z, b2.z, fmaf(a.w, b3.z, acc[2]))));
    acc[3] = fmaf(a.x, b0.w, fmaf(a.y, b1.w, fmaf(a.z, b2.w, fmaf(a.w, b3.w, acc[3]))));
}

__global__ __launch_bounds__(256) void update_kernel(
    float* __restrict__ out, const float* __restrict__ rs,
    const int* __restrict__ init_f, const int* __restrict__ sel_f,
    float* __restrict__ rb, int p)
{
    const int ag = blockIdx.x;
    if (!(init_f[ag] && sel_f[ag])) return;
    const int ct = blockIdx.y + (blockIdx.y >= p ? 1 : 0);
    float* M = out + COV_OFF + (size_t)ag * D * D;
    const int j0 = p * NB, c0 = ct * NB;
    const float c = rs[ag] + 1.0f;
    const float c2 = c * c;
    __shared__ float R[NB][NB + 8];
    __shared__ float F[NB][NB + 8];
    const int t = threadIdx.x;
    {   // R from the race-free stash
        const float* rsrc = rb + RBOFF(p & 1, ag, ct);
        for (int idx = t; idx < NB * 15; idx += 256) {
            int k = idx / 15, q = idx % 15;
            *(float4*)&R[k][4 * q] = *(const float4*)(rsrc + k * NB + 4 * q);
        }
    }
    const int tx = t % 16, ty = t / 16;
    for (int rr = 0; rr < 2; ++rr) {
        const int rt = (int)blockIdx.z * 2 + rr;
        const int r0 = rt * NB;
        __syncthreads();
        for (int idx = t; idx < NB * 15; idx += 256) {
            int rrw = idx / 15, q = idx % 15;
            *(float4*)&F[rrw][4 * q] = *(const float4*)(M + (size_t)(r0 + rrw) * D + j0 + 4 * q);
        }
        __syncthreads();
        if (tx < 15 && ty < 15) {
            float acc[4][4];
            #pragma unroll
            for (int i = 0; i < 4; ++i)
                #pragma unroll
                for (int j = 0; j < 4; ++j) acc[i][j] = 0.0f;
            for (int kq = 0; kq < 15; ++kq) {
                float4 a0 = *(const float4*)&F[4 * ty + 0][4 * kq];
                float4 a1 = *(const float4*)&F[4 * ty + 1][4 * kq];
                float4 a2 = *(const float4*)&F[4 * ty + 2][4 * kq];
                float4 a3 = *(const float4*)&F[4 * ty + 3][4 * kq];
                float4 b0 = *(const float4*)&R[4 * kq + 0][4 * tx];
                float4 b1 = *(const float4*)&R[4 * kq + 1][4 * tx];
                float4 b2 = *(const float4*)&R[4 * kq + 2][4 * tx];
                float4 b3 = *(const float4*)&R[4 * kq + 3][4 * tx];
                mm_row(a0, b0, b1, b2, b3, acc[0]);
                mm_row(a1, b0, b1, b2, b3, acc[1]);
                mm_row(a2, b0, b1, b2, b3, acc[2]);
                mm_row(a3, b0, b1, b2, b3, acc[3]);
            }
            #pragma unroll
            for (int i = 0; i < 4; ++i) {
                const int rg = r0 + 4 * ty + i;
                float* dst = M + (size_t)rg * D + c0 + 4 * tx;
                float4 base;
                if (rt == p) { base = make_float4(0.f, 0.f, 0.f, 0.f); }
                else         { base = *(const float4*)dst; }
                float4 v;
                v.x = base.x + acc[i][0];
                v.y = base.y + acc[i][1];
                v.z = base.z + acc[i][2];
                v.w = base.w + acc[i][3];
                if (p < NPAN - 1) {
                    // stash next pass's R slice (rows of next panel, this col-tile)
                    if (rt == p + 1 && ct != p + 1) {
                        float* rdst = rb + RBOFF((p + 1) & 1, ag, ct) + (4 * ty + i) * NB + 4 * tx;
                        *(float4*)rdst = v;
                    }
                    *(float4*)dst = v;
                } else {
                    // last pass: fold finalize  cov = c*I - c^2 * Sinv
                    const int cg = c0 + 4 * tx;
                    float4 o;
                    o.x = ((rg == cg + 0) ? c : 0.f) - c2 * v.x;
                    o.y = ((rg == cg + 1) ? c : 0.f) - c2 * v.y;
                    o.z = ((rg == cg + 2) ? c : 0.f) - c2 * v.z;
                    o.w = ((rg == cg + 3) ? c : 0.f) - c2 * v.w;
                    *(float4*)dst = o;
                }
            }
        }
    }
}

// ------- fin_panel: affine-transform the last panel's columns (300..359) -----
__global__ __launch_bounds__(384) void fin_panel_kernel(
    float* __restrict__ out, const float* __restrict__ rs,
    const int* __restrict__ init_f, const int* __restrict__ sel_f)
{
    const int ag = blockIdx.x;
    if (!(init_f[ag] && sel_f[ag])) return;
    const int t = threadIdx.x;
    if (t >= 360) return;
    const float c = rs[ag] + 1.0f;
    const float c2 = c * c;
    float* cov = out + COV_OFF + (size_t)ag * D * D;
    const int r = (int)blockIdx.y * 6 + t / 60;
    const int cc = (NPAN - 1) * NB + (t % 60);
    const float v = cov[(size_t)r * D + cc];
    cov[(size_t)r * D + cc] = ((r == cc) ? c : 0.f) - c2 * v;
}

// ------- mean: m = obs - c*Sinv*d, via transformed C:  m = obs - d + (C^T d)/c
__global__ __launch_bounds__(384) void solve_mean_kernel(
    float* __restrict__ out, const float* __restrict__ mean_in,
    const float* __restrict__ obs, const float* __restrict__ rs,
    const int* __restrict__ init_f, const int* __restrict__ sel_f)
{
    const int ag = blockIdx.x;
    if (!(init_f[ag] && sel_f[ag])) return;
    const float* C = out + COV_OFF + (size_t)ag * D * D;
    __shared__ float dsh[D];
    const int t = threadIdx.x;
    if (t < D) dsh[t] = obs[ag * D + t] - mean_in[ag * D + gshift(t)];
    __syncthreads();
    if (t < D) {
        float dot = 0.0f;
        #pragma unroll 8
        for (int j = 0; j < D; ++j)
            dot = fmaf(C[(size_t)j * D + t], dsh[j], dot);   // coalesced col read
        const float c = rs[ag] + 1.0f;
        out[ag * D + t] = obs[ag * D + t] - dsh[t] + dot / c;
    }
}

extern "C" void kernel_launch(void* const* d_in, const int* in_sizes, int n_in,
                              void* d_out, int out_size, void* d_ws, size_t ws_size,
                              hipStream_t stream) {
    const float* mean_in     = (const float*)d_in[0];
    const float* P           = (const float*)d_in[1];
    const float* obs         = (const float*)d_in[2];
    const float* rs          = (const float*)d_in[3];
    const int*   initialized = (const int*)d_in[4];
    const int*   selected    = (const int*)d_in[5];
    float* out = (float*)d_out;
    float* rb  = (float*)d_ws;   // 2*64*6*3600 floats = 11.1 MB

    build_kernel<<<dim3(46, NAG), 384, 0, stream>>>(P, mean_in, obs, rs,
                                                    initialized, selected, out, rb);
    for (int p = 0; p < NPAN; ++p) {
        factor_kernel<<<NAG, 384, 0, stream>>>(out, initialized, selected, rb, p);
        update_kernel<<<dim3(NAG, NPAN - 1, 3), 256, 0, stream>>>(out, rs, initialized,
                                                                  selected, rb, p);
    }
    fin_panel_kernel<<<dim3(NAG, 60), 384, 0, stream>>>(out, rs, initialized, selected);
    solve_mean_kernel<<<NAG, 384, 0, stream>>>(out, mean_in, obs, rs, initialized, selected);
}